// Round 5
// baseline (84.331 us; speedup 1.0000x reference)
//
#include <hip/hip_runtime.h>
#include <math.h>
#include <stdint.h>

#define NB1   4096
#define NBTOT 8192
#define NFD   128
#define QCOLS 2048
#define BROWS 128
#define BCOLS 64
#define NTILES (QCOLS / BCOLS)   // 32

typedef __attribute__((ext_vector_type(8))) short bf16x8;
typedef __attribute__((ext_vector_type(4))) float f32x4;
typedef unsigned short u16;

__device__ __forceinline__ u16 f2bf(float x) {
    unsigned u = __builtin_bit_cast(unsigned, x);
    unsigned r = u + 0x7fffu + ((u >> 16) & 1u);   // RNE (inputs finite/normal)
    return (u16)(r >> 16);
}
__device__ __forceinline__ float bf2f(u16 h) {
    return __builtin_bit_cast(float, ((unsigned)h) << 16);
}

// async 16B global->LDS; lds base wave-uniform, HW adds lane*16
__device__ __forceinline__ void gl16(const u16* g, char* l) {
    __builtin_amdgcn_global_load_lds(
        (const __attribute__((address_space(1))) unsigned int*)g,
        (__attribute__((address_space(3))) unsigned int*)l,
        16, 0, 0);
}

// ---------------------------------------------------------------------------
// Kernel 1: row L2-normalize -> bf16 hi/lo split. One wave per row.
// ---------------------------------------------------------------------------
__global__ void norm_k(const float* __restrict__ f1, const float* __restrict__ f2,
                       u16* __restrict__ nfh, u16* __restrict__ nfl) {
    const int w = threadIdx.x >> 6, lane = threadIdx.x & 63;
    const int row = blockIdx.x * 4 + w;
    const float* src = (row < NB1) ? (f1 + (size_t)row * NFD)
                                   : (f2 + (size_t)(row - NB1) * NFD);
    const float2 v = *reinterpret_cast<const float2*>(src + 2 * lane);
    float s = v.x * v.x + v.y * v.y;
#pragma unroll
    for (int m = 32; m >= 1; m >>= 1) s += __shfl_xor(s, m, 64);
    const float inv = 1.0f / fmaxf(sqrtf(s), 1e-12f);
    const float x0 = v.x * inv, x1 = v.y * inv;
    const u16 h0 = f2bf(x0), h1 = f2bf(x1);
    const u16 l0 = f2bf(x0 - bf2f(h0)), l1 = f2bf(x1 - bf2f(h1));
    ((unsigned*)(nfh + (size_t)row * NFD))[lane] = (unsigned)h0 | ((unsigned)h1 << 16);
    ((unsigned*)(nfl + (size_t)row * NFD))[lane] = (unsigned)l0 | ((unsigned)l1 << 16);
}

// ---------------------------------------------------------------------------
// Kernel 2: MFMA sim-stats. Grid (4 quarters, 64 row-tiles), 256 thr = 4 waves
// (wave w owns rows 32w..32w+31, ALL 64 cols; fa=2, fb=4). 2 blocks/CU.
// A-frags in registers (tile-invariant). LDS = B dbuf 2 x (H 16K + L 16K).
// 4-bit XOR swizzle, staged via global_load_lds w/ pre-swizzled source.
// sim = Ah*Bh + Ah*Bl + Al*Bh (lo*lo dropped ~2^-18).
// Inner loop: explicit ks ping-pong (set0/set1) + setprio around MFMA cluster.
// ---------------------------------------------------------------------------
__global__ __launch_bounds__(256, 2) void simstat_mfma(const u16* __restrict__ nfh,
                                                       const u16* __restrict__ nfl,
                                                       float* __restrict__ posp,
                                                       float* __restrict__ sexpp) {
    extern __shared__ __align__(16) char smem[];   // 65536 = 2 x (H 16K + L 16K)

    const int q    = blockIdx.x;
    const int rt   = blockIdx.y;
    const int row0 = rt * BROWS;
    const int col0q = q * QCOLS;
    const bool same = ((row0 >= NB1) == (q >= 2));
    const int p = q & 1;

    const int t    = threadIdx.x;
    const int w    = t >> 6;
    const int lane = t & 63;
    const int lr   = lane & 15;
    const int lg   = lane >> 4;
    const int rowbase = 32 * w;

    // ---- precompute stage mapping (loop-invariant) ----
    int goffs[4], dbase[4];
#pragma unroll
    for (int i = 0; i < 4; ++i) {
        const int base = w * 4096 + i * 1024;
        const int d    = base + lane * 16;
        const int sr   = d >> 8;            // dest row 0..63
        const int slot = (d >> 4) & 15;
        const int kc   = slot ^ (sr & 15);  // source k-chunk (involution)
        goffs[i] = sr * NFD + kc * 8;
        dbase[i] = base;
    }
    // read offsets
    int rbo[4], koff[4];
#pragma unroll
    for (int fb = 0; fb < 4; ++fb) rbo[fb] = (16 * fb + lr) * 256;
#pragma unroll
    for (int ks = 0; ks < 4; ++ks) koff[ks] = (((ks << 2) + lg) ^ lr) << 4;

    // ---- stage B tile 0 (async) ----
    {
        const u16* gh = nfh + (size_t)col0q * NFD;
        const u16* gl = nfl + (size_t)col0q * NFD;
#pragma unroll
        for (int i = 0; i < 4; ++i) {
            gl16(gh + goffs[i], smem + dbase[i]);
            gl16(gl + goffs[i], smem + 16384 + dbase[i]);
        }
    }

    // ---- A fragments -> registers (tile-invariant) ----
    bf16x8 ah[4][2], al[4][2];
#pragma unroll
    for (int ks = 0; ks < 4; ++ks)
#pragma unroll
        for (int fa = 0; fa < 2; ++fa) {
            const size_t off = (size_t)(row0 + rowbase + 16 * fa + lr) * NFD + 32 * ks + 8 * lg;
            ah[ks][fa] = *reinterpret_cast<const bf16x8*>(nfh + off);
            al[ks][fa] = *reinterpret_cast<const bf16x8*>(nfl + off);
        }

    __syncthreads();   // tile0 + A loads complete

    float stat[2][4];
#pragma unroll
    for (int fa = 0; fa < 2; ++fa)
#pragma unroll
        for (int r = 0; r < 4; ++r) stat[fa][r] = same ? -3.0e38f : 0.0f;
    const float K2 = 1.44269504089f / 0.07f;   // log2(e)/tau
    const float invtau = 1.0f / 0.07f;

#define LOADB(ks_, BH_, BL_)                                                  \
    {                                                                         \
        _Pragma("unroll")                                                     \
        for (int fb = 0; fb < 4; ++fb) {                                      \
            BH_[fb] = *(const bf16x8*)(bufH + rbo[fb] + koff[ks_]);           \
            BL_[fb] = *(const bf16x8*)(bufL + rbo[fb] + koff[ks_]);           \
        }                                                                     \
    }
#define MFMAS(ks_, BH_, BL_)                                                  \
    {                                                                         \
        __builtin_amdgcn_s_setprio(1);                                        \
        _Pragma("unroll")                                                     \
        for (int fb = 0; fb < 4; ++fb)                                        \
            _Pragma("unroll")                                                 \
            for (int fa = 0; fa < 2; ++fa) {                                  \
                acc[fa][fb] = __builtin_amdgcn_mfma_f32_16x16x32_bf16(ah[ks_][fa], BH_[fb], acc[fa][fb], 0, 0, 0); \
                acc[fa][fb] = __builtin_amdgcn_mfma_f32_16x16x32_bf16(ah[ks_][fa], BL_[fb], acc[fa][fb], 0, 0, 0); \
                acc[fa][fb] = __builtin_amdgcn_mfma_f32_16x16x32_bf16(al[ks_][fa], BH_[fb], acc[fa][fb], 0, 0, 0); \
            }                                                                 \
        __builtin_amdgcn_s_setprio(0);                                        \
    }

#pragma unroll 1
    for (int tile = 0; tile < NTILES; ++tile) {
        const char* bufH = smem + (tile & 1) * 32768;
        const char* bufL = bufH + 16384;

        // issue next-tile stage early (lands during compute, drained at barrier)
        if (tile + 1 < NTILES) {
            char* nb = smem + ((tile + 1) & 1) * 32768;
            const u16* gh = nfh + (size_t)(col0q + (tile + 1) * BCOLS) * NFD;
            const u16* gl = nfl + (size_t)(col0q + (tile + 1) * BCOLS) * NFD;
#pragma unroll
            for (int i = 0; i < 4; ++i) {
                gl16(gh + goffs[i], nb + dbase[i]);
                gl16(gl + goffs[i], nb + 16384 + dbase[i]);
            }
        }

        f32x4 acc[2][4];
#pragma unroll
        for (int fa = 0; fa < 2; ++fa)
#pragma unroll
            for (int fb = 0; fb < 4; ++fb) {
                f32x4 z = {0.0f, 0.0f, 0.0f, 0.0f};
                acc[fa][fb] = z;
            }

        // ks software pipeline: depth-2 prologue, ping-pong sets
        bf16x8 bh0[4], bl0[4], bh1[4], bl1[4];
        LOADB(0, bh0, bl0);
        LOADB(1, bh1, bl1);
        MFMAS(0, bh0, bl0);
        LOADB(2, bh0, bl0);
        MFMAS(1, bh1, bl1);
        LOADB(3, bh1, bl1);
        MFMAS(2, bh0, bl0);
        MFMAS(3, bh1, bl1);

        // fold acc into stat; C/D: col=lane&15, row=4*lg+reg (m89-verified)
        if (same) {
            const int col0 = col0q + tile * BCOLS;
#pragma unroll
            for (int fa = 0; fa < 2; ++fa)
#pragma unroll
                for (int fb = 0; fb < 4; ++fb)
#pragma unroll
                    for (int r = 0; r < 4; ++r) {
                        const int grow = row0 + rowbase + 16 * fa + 4 * lg + r;
                        const int gcol = col0 + 16 * fb + lr;
                        stat[fa][r] = (grow == gcol) ? stat[fa][r]
                                                     : fmaxf(stat[fa][r], acc[fa][fb][r]);
                    }
        } else {
#pragma unroll
            for (int fa = 0; fa < 2; ++fa)
#pragma unroll
                for (int fb = 0; fb < 4; ++fb)
#pragma unroll
                    for (int r = 0; r < 4; ++r)
                        stat[fa][r] += exp2f(acc[fa][fb][r] * K2);
        }

        __syncthreads();
    }
#undef LOADB
#undef MFMAS

    // reduce over the 16 columns held across lr (lane bits 0..3)
#pragma unroll
    for (int m = 1; m <= 8; m <<= 1) {
#pragma unroll
        for (int fa = 0; fa < 2; ++fa)
#pragma unroll
            for (int r = 0; r < 4; ++r) {
                const float o = __shfl_xor(stat[fa][r], m, 64);
                stat[fa][r] = same ? fmaxf(stat[fa][r], o) : (stat[fa][r] + o);
            }
    }
    // lanes lr==0 (one per lg) hold complete rows: rowbase+16*fa+4*lg+r
    if (lr == 0) {
        float* dst = (same ? posp : sexpp) + (size_t)p * NBTOT + row0 + rowbase;
#pragma unroll
        for (int fa = 0; fa < 2; ++fa)
#pragma unroll
            for (int r = 0; r < 4; ++r) {
                const float v = same ? stat[fa][r] * invtau : stat[fa][r];
                dst[16 * fa + 4 * lg + r] = v;
            }
    }
}

// ---------------------------------------------------------------------------
// Kernel 3: combine quarter-partials, per-row loss, mean. One block.
// loss_i = log(exp(pos)+S) - pos = log1p(S * exp(-pos))
// ---------------------------------------------------------------------------
__global__ void loss_k(const float* __restrict__ posp, const float* __restrict__ sexpp,
                       float* __restrict__ out) {
    const int t = threadIdx.x;  // 256
    float s = 0.0f;
    for (int i = t; i < NBTOT; i += 256) {
        const float pv = fmaxf(posp[i], posp[NBTOT + i]);
        const float se = sexpp[i] + sexpp[NBTOT + i];
        s += log1pf(se * __expf(-pv));
    }
#pragma unroll
    for (int m = 32; m >= 1; m >>= 1) s += __shfl_xor(s, m, 64);
    __shared__ float part[4];
    if ((t & 63) == 0) part[t >> 6] = s;
    __syncthreads();
    if (t == 0) out[0] = (part[0] + part[1] + part[2] + part[3]) / (float)NBTOT;
}

// ---------------------------------------------------------------------------
extern "C" void kernel_launch(void* const* d_in, const int* in_sizes, int n_in,
                              void* d_out, int out_size, void* d_ws, size_t ws_size,
                              hipStream_t stream) {
    const float* f1 = (const float*)d_in[0];
    const float* f2 = (const float*)d_in[1];

    u16*   nfh   = (u16*)d_ws;                       // 8192*128 bf16 = 2 MB
    u16*   nfl   = nfh + (size_t)NBTOT * NFD;        // 2 MB
    float* posp  = (float*)(nfl + (size_t)NBTOT * NFD);
    float* sexpp = posp + 2 * NBTOT;

    (void)hipFuncSetAttribute(reinterpret_cast<const void*>(simstat_mfma),
                              hipFuncAttributeMaxDynamicSharedMemorySize, 65536);

    norm_k<<<NBTOT / 4, 256, 0, stream>>>(f1, f2, nfh, nfl);
    simstat_mfma<<<dim3(4, 64), 256, 65536, stream>>>(nfh, nfl, posp, sexpp);
    loss_k<<<1, 256, 0, stream>>>(posp, sexpp, (float*)d_out);
}

// Round 6
// 78.213 us; speedup vs baseline: 1.0782x; 1.0782x over previous
//
#include <hip/hip_runtime.h>
#include <math.h>
#include <stdint.h>

#define NB1   4096
#define NBTOT 8192
#define NFD   128
#define ECOLS 1024               // columns per block (one "eighth")
#define BROWS 128
#define BCOLS 64
#define NTILES (ECOLS / BCOLS)   // 16

typedef __attribute__((ext_vector_type(8))) short bf16x8;
typedef __attribute__((ext_vector_type(4))) float f32x4;
typedef unsigned short u16;

__device__ __forceinline__ u16 f2bf(float x) {
    unsigned u = __builtin_bit_cast(unsigned, x);
    unsigned r = u + 0x7fffu + ((u >> 16) & 1u);   // RNE (inputs finite/normal)
    return (u16)(r >> 16);
}
__device__ __forceinline__ float bf2f(u16 h) {
    return __builtin_bit_cast(float, ((unsigned)h) << 16);
}

// async 16B global->LDS; lds base wave-uniform, HW adds lane*16
__device__ __forceinline__ void gl16(const u16* g, char* l) {
    __builtin_amdgcn_global_load_lds(
        (const __attribute__((address_space(1))) unsigned int*)g,
        (__attribute__((address_space(3))) unsigned int*)l,
        16, 0, 0);
}

// ---------------------------------------------------------------------------
// Kernel 1: row L2-normalize -> bf16 hi/lo split. One wave per row.
// ---------------------------------------------------------------------------
__global__ void norm_k(const float* __restrict__ f1, const float* __restrict__ f2,
                       u16* __restrict__ nfh, u16* __restrict__ nfl) {
    const int w = threadIdx.x >> 6, lane = threadIdx.x & 63;
    const int row = blockIdx.x * 4 + w;
    const float* src = (row < NB1) ? (f1 + (size_t)row * NFD)
                                   : (f2 + (size_t)(row - NB1) * NFD);
    const float2 v = *reinterpret_cast<const float2*>(src + 2 * lane);
    float s = v.x * v.x + v.y * v.y;
#pragma unroll
    for (int m = 32; m >= 1; m >>= 1) s += __shfl_xor(s, m, 64);
    const float inv = 1.0f / fmaxf(sqrtf(s), 1e-12f);
    const float x0 = v.x * inv, x1 = v.y * inv;
    const u16 h0 = f2bf(x0), h1 = f2bf(x1);
    const u16 l0 = f2bf(x0 - bf2f(h0)), l1 = f2bf(x1 - bf2f(h1));
    ((unsigned*)(nfh + (size_t)row * NFD))[lane] = (unsigned)h0 | ((unsigned)h1 << 16);
    ((unsigned*)(nfl + (size_t)row * NFD))[lane] = (unsigned)l0 | ((unsigned)l1 << 16);
}

// ---------------------------------------------------------------------------
// Kernel 2: MFMA sim-stats. Grid (8 col-eighths, 64 row-tiles) = 512 blocks
// = 2 independent blocks/CU (desynced overlap, m114). 256 thr = 4 waves; wave
// w owns rows 32w..32w+31 (fa=2), ALL 64 tile cols (fb=4).
// A-frags register-resident (tile-invariant). LDS = B dbuf 2 x (H16K + L16K)
// = 64KB. 4-bit XOR swizzle; staged via global_load_lds, pre-swizzled source.
// sim = Ah*Bh + Ah*Bl + Al*Bh (lo*lo dropped ~2^-18).
// Partials: 4 per class per row -> posp[4][8192], sexpp[4][8192].
// ---------------------------------------------------------------------------
__global__ __launch_bounds__(256, 2) void simstat_mfma(const u16* __restrict__ nfh,
                                                       const u16* __restrict__ nfl,
                                                       float* __restrict__ posp,
                                                       float* __restrict__ sexpp) {
    extern __shared__ __align__(16) char smem[];   // 65536 = 2 x (H 16K + L 16K)

    const int e    = blockIdx.x;          // column eighth 0..7
    const int rt   = blockIdx.y;
    const int row0 = rt * BROWS;
    const int col0e = e * ECOLS;
    const bool same = ((row0 >= NB1) == (e >= 4));
    const int p = e & 3;

    const int t    = threadIdx.x;
    const int w    = t >> 6;
    const int lane = t & 63;
    const int lr   = lane & 15;
    const int lg   = lane >> 4;
    const int rowbase = 32 * w;

    // ---- precompute stage mapping (loop-invariant) ----
    int goffs[4], dbase[4];
#pragma unroll
    for (int i = 0; i < 4; ++i) {
        const int base = w * 4096 + i * 1024;
        const int d    = base + lane * 16;
        const int sr   = d >> 8;            // dest row 0..63
        const int slot = (d >> 4) & 15;
        const int kc   = slot ^ (sr & 15);  // source k-chunk (involution)
        goffs[i] = sr * NFD + kc * 8;
        dbase[i] = base;
    }
    // read offsets
    int rbo[4], koff[4];
#pragma unroll
    for (int fb = 0; fb < 4; ++fb) rbo[fb] = (16 * fb + lr) * 256;
#pragma unroll
    for (int ks = 0; ks < 4; ++ks) koff[ks] = (((ks << 2) + lg) ^ lr) << 4;

    // ---- stage B tile 0 (async) ----
    {
        const u16* gh = nfh + (size_t)col0e * NFD;
        const u16* gl = nfl + (size_t)col0e * NFD;
#pragma unroll
        for (int i = 0; i < 4; ++i) {
            gl16(gh + goffs[i], smem + dbase[i]);
            gl16(gl + goffs[i], smem + 16384 + dbase[i]);
        }
    }

    // ---- A fragments -> registers (tile-invariant) ----
    bf16x8 ah[4][2], al[4][2];
#pragma unroll
    for (int ks = 0; ks < 4; ++ks)
#pragma unroll
        for (int fa = 0; fa < 2; ++fa) {
            const size_t off = (size_t)(row0 + rowbase + 16 * fa + lr) * NFD + 32 * ks + 8 * lg;
            ah[ks][fa] = *reinterpret_cast<const bf16x8*>(nfh + off);
            al[ks][fa] = *reinterpret_cast<const bf16x8*>(nfl + off);
        }

    __syncthreads();   // tile0 + A loads complete

    float stat[2][4];
#pragma unroll
    for (int fa = 0; fa < 2; ++fa)
#pragma unroll
        for (int r = 0; r < 4; ++r) stat[fa][r] = same ? -3.0e38f : 0.0f;
    const float K2 = 1.44269504089f / 0.07f;   // log2(e)/tau
    const float invtau = 1.0f / 0.07f;

#define LOADB(ks_, BH_, BL_)                                                  \
    {                                                                         \
        _Pragma("unroll")                                                     \
        for (int fb = 0; fb < 4; ++fb) {                                      \
            BH_[fb] = *(const bf16x8*)(bufH + rbo[fb] + koff[ks_]);           \
            BL_[fb] = *(const bf16x8*)(bufL + rbo[fb] + koff[ks_]);           \
        }                                                                     \
    }
#define MFMAS(ks_, BH_, BL_)                                                  \
    {                                                                         \
        __builtin_amdgcn_s_setprio(1);                                        \
        _Pragma("unroll")                                                     \
        for (int fb = 0; fb < 4; ++fb)                                        \
            _Pragma("unroll")                                                 \
            for (int fa = 0; fa < 2; ++fa) {                                  \
                acc[fa][fb] = __builtin_amdgcn_mfma_f32_16x16x32_bf16(ah[ks_][fa], BH_[fb], acc[fa][fb], 0, 0, 0); \
                acc[fa][fb] = __builtin_amdgcn_mfma_f32_16x16x32_bf16(ah[ks_][fa], BL_[fb], acc[fa][fb], 0, 0, 0); \
                acc[fa][fb] = __builtin_amdgcn_mfma_f32_16x16x32_bf16(al[ks_][fa], BH_[fb], acc[fa][fb], 0, 0, 0); \
            }                                                                 \
        __builtin_amdgcn_s_setprio(0);                                        \
    }

#pragma unroll 1
    for (int tile = 0; tile < NTILES; ++tile) {
        const char* bufH = smem + (tile & 1) * 32768;
        const char* bufL = bufH + 16384;

        // issue next-tile stage early (lands during compute, drained at barrier)
        if (tile + 1 < NTILES) {
            char* nb = smem + ((tile + 1) & 1) * 32768;
            const u16* gh = nfh + (size_t)(col0e + (tile + 1) * BCOLS) * NFD;
            const u16* gl = nfl + (size_t)(col0e + (tile + 1) * BCOLS) * NFD;
#pragma unroll
            for (int i = 0; i < 4; ++i) {
                gl16(gh + goffs[i], nb + dbase[i]);
                gl16(gl + goffs[i], nb + 16384 + dbase[i]);
            }
        }

        f32x4 acc[2][4];
#pragma unroll
        for (int fa = 0; fa < 2; ++fa)
#pragma unroll
            for (int fb = 0; fb < 4; ++fb) {
                f32x4 z = {0.0f, 0.0f, 0.0f, 0.0f};
                acc[fa][fb] = z;
            }

        // ks software pipeline: depth-2 prologue, ping-pong sets
        bf16x8 bh0[4], bl0[4], bh1[4], bl1[4];
        LOADB(0, bh0, bl0);
        LOADB(1, bh1, bl1);
        MFMAS(0, bh0, bl0);
        LOADB(2, bh0, bl0);
        MFMAS(1, bh1, bl1);
        LOADB(3, bh1, bl1);
        MFMAS(2, bh0, bl0);
        MFMAS(3, bh1, bl1);

        // fold acc into stat; C/D: col=lane&15, row=4*lg+reg (m89-verified)
        if (same) {
            const int col0 = col0e + tile * BCOLS;
#pragma unroll
            for (int fa = 0; fa < 2; ++fa)
#pragma unroll
                for (int fb = 0; fb < 4; ++fb)
#pragma unroll
                    for (int r = 0; r < 4; ++r) {
                        const int grow = row0 + rowbase + 16 * fa + 4 * lg + r;
                        const int gcol = col0 + 16 * fb + lr;
                        stat[fa][r] = (grow == gcol) ? stat[fa][r]
                                                     : fmaxf(stat[fa][r], acc[fa][fb][r]);
                    }
        } else {
#pragma unroll
            for (int fa = 0; fa < 2; ++fa)
#pragma unroll
                for (int fb = 0; fb < 4; ++fb)
#pragma unroll
                    for (int r = 0; r < 4; ++r)
                        stat[fa][r] += exp2f(acc[fa][fb][r] * K2);
        }

        __syncthreads();
    }
#undef LOADB
#undef MFMAS

    // reduce over the 16 columns held across lr (lane bits 0..3)
#pragma unroll
    for (int m = 1; m <= 8; m <<= 1) {
#pragma unroll
        for (int fa = 0; fa < 2; ++fa)
#pragma unroll
            for (int r = 0; r < 4; ++r) {
                const float o = __shfl_xor(stat[fa][r], m, 64);
                stat[fa][r] = same ? fmaxf(stat[fa][r], o) : (stat[fa][r] + o);
            }
    }
    // lanes lr==0 (one per lg) hold complete rows: rowbase+16*fa+4*lg+r
    if (lr == 0) {
        float* dst = (same ? posp : sexpp) + (size_t)p * NBTOT + row0 + rowbase;
#pragma unroll
        for (int fa = 0; fa < 2; ++fa)
#pragma unroll
            for (int r = 0; r < 4; ++r) {
                const float v = same ? stat[fa][r] * invtau : stat[fa][r];
                dst[16 * fa + 4 * lg + r] = v;
            }
    }
}

// ---------------------------------------------------------------------------
// Kernel 3: combine 4 partials/class, per-row loss, mean. One block.
// loss_i = log(exp(pos)+S) - pos = log1p(S * exp(-pos))
// ---------------------------------------------------------------------------
__global__ void loss_k(const float* __restrict__ posp, const float* __restrict__ sexpp,
                       float* __restrict__ out) {
    const int t = threadIdx.x;  // 256
    float s = 0.0f;
    for (int i = t; i < NBTOT; i += 256) {
        const float pv = fmaxf(fmaxf(posp[i], posp[NBTOT + i]),
                               fmaxf(posp[2 * NBTOT + i], posp[3 * NBTOT + i]));
        const float se = sexpp[i] + sexpp[NBTOT + i] + sexpp[2 * NBTOT + i] + sexpp[3 * NBTOT + i];
        s += log1pf(se * __expf(-pv));
    }
#pragma unroll
    for (int m = 32; m >= 1; m >>= 1) s += __shfl_xor(s, m, 64);
    __shared__ float part[4];
    if ((t & 63) == 0) part[t >> 6] = s;
    __syncthreads();
    if (t == 0) out[0] = (part[0] + part[1] + part[2] + part[3]) / (float)NBTOT;
}

// ---------------------------------------------------------------------------
extern "C" void kernel_launch(void* const* d_in, const int* in_sizes, int n_in,
                              void* d_out, int out_size, void* d_ws, size_t ws_size,
                              hipStream_t stream) {
    const float* f1 = (const float*)d_in[0];
    const float* f2 = (const float*)d_in[1];

    u16*   nfh   = (u16*)d_ws;                       // 8192*128 bf16 = 2 MB
    u16*   nfl   = nfh + (size_t)NBTOT * NFD;        // 2 MB
    float* posp  = (float*)(nfl + (size_t)NBTOT * NFD);  // 4*8192 f32
    float* sexpp = posp + 4 * NBTOT;                     // 4*8192 f32

    (void)hipFuncSetAttribute(reinterpret_cast<const void*>(simstat_mfma),
                              hipFuncAttributeMaxDynamicSharedMemorySize, 65536);

    norm_k<<<NBTOT / 4, 256, 0, stream>>>(f1, f2, nfh, nfl);
    simstat_mfma<<<dim3(8, 64), 256, 65536, stream>>>(nfh, nfl, posp, sexpp);
    loss_k<<<1, 256, 0, stream>>>(posp, sexpp, (float*)d_out);
}

// Round 8
// 40.405 us; speedup vs baseline: 2.0871x; 1.9357x over previous
//
#include <hip/hip_runtime.h>
#include <math.h>
#include <stdint.h>

#define NB1   4096
#define NBTOT 8192
#define NFD   128
#define ECOLS 1024               // columns per block (one "eighth")
#define BROWS 128
#define BCOLS 128
#define NTILES (ECOLS / BCOLS)   // 8

typedef __attribute__((ext_vector_type(8))) _Float16 f16x8;
typedef __attribute__((ext_vector_type(4))) float f32x4;
typedef _Float16 f16;

// async 16B global->LDS; lds base wave-uniform, HW adds lane*16
__device__ __forceinline__ void gl16(const f16* g, char* l) {
    __builtin_amdgcn_global_load_lds(
        (const __attribute__((address_space(1))) unsigned int*)g,
        (__attribute__((address_space(3))) unsigned int*)l,
        16, 0, 0);
}

// ---------------------------------------------------------------------------
// Kernel 1: row L2-normalize -> fp16 (single precision-split pass is enough:
// fp16 dot error <= ~4.9e-4 abs -> +-0.007 logits -> loss err ~0.015 << 0.0925).
// One wave per row.
// ---------------------------------------------------------------------------
__global__ void norm_k(const float* __restrict__ f1, const float* __restrict__ f2,
                       f16* __restrict__ nfh) {
    const int w = threadIdx.x >> 6, lane = threadIdx.x & 63;
    const int row = blockIdx.x * 4 + w;
    const float* src = (row < NB1) ? (f1 + (size_t)row * NFD)
                                   : (f2 + (size_t)(row - NB1) * NFD);
    const float2 v = *reinterpret_cast<const float2*>(src + 2 * lane);
    float s = v.x * v.x + v.y * v.y;
#pragma unroll
    for (int m = 32; m >= 1; m >>= 1) s += __shfl_xor(s, m, 64);
    const float inv = 1.0f / fmaxf(sqrtf(s), 1e-12f);
    const f16 h0 = (f16)(v.x * inv);
    const f16 h1 = (f16)(v.y * inv);
    const unsigned pack = (unsigned)__builtin_bit_cast(unsigned short, h0) |
                          ((unsigned)__builtin_bit_cast(unsigned short, h1) << 16);
    ((unsigned*)(nfh + (size_t)row * NFD))[lane] = pack;
}

// ---------------------------------------------------------------------------
// Kernel 2: fp16 MFMA sim-stats, single pass. Grid (8 col-eighths, 64 row
// tiles) = 512 blocks = 2 independent blocks/CU. 256 thr = 4 waves in a 2x2
// wave grid over the 128x128 tile: wave w -> rows 64*(w>>1)+..., cols
// 64*(w&1)+... (fa=4, fb=4) so each wave reads only half the B tile.
// A-frags register-resident (tile-invariant, 64 VGPR). LDS = B dbuf 2x32KB.
// 4-bit XOR swizzle on 16B slots; staged via global_load_lds, pre-swizzled
// source (conflict-free per 16-lane phase, measured 0).
// ---------------------------------------------------------------------------
__global__ __launch_bounds__(256, 2) void simstat_mfma(const f16* __restrict__ nfh,
                                                       float* __restrict__ posp,
                                                       float* __restrict__ sexpp) {
    extern __shared__ __align__(16) char smem[];   // 65536 = 2 x 32KB

    const int e    = blockIdx.x;          // column eighth 0..7
    const int rt   = blockIdx.y;
    const int row0 = rt * BROWS;
    const int col0e = e * ECOLS;
    const bool same = ((row0 >= NB1) == (e >= 4));
    const int p = e & 3;

    const int t    = threadIdx.x;
    const int w    = t >> 6;
    const int lane = t & 63;
    const int lr   = lane & 15;
    const int lg   = lane >> 4;
    const int rowbase = 64 * (w >> 1);
    const int colbase = 64 * (w & 1);

    // ---- precompute stage mapping (loop-invariant): 8KB per wave ----
    int goffs[8], dbase[8];
#pragma unroll
    for (int i = 0; i < 8; ++i) {
        const int base = w * 8192 + i * 1024;
        const int d    = base + lane * 16;
        const int sr   = d >> 8;            // dest row 0..127
        const int slot = (d >> 4) & 15;
        const int kc   = slot ^ (sr & 15);  // source k-chunk (involution)
        goffs[i] = sr * NFD + kc * 8;
        dbase[i] = base;
    }
    // read offsets
    int rbo[4], koff[4];
#pragma unroll
    for (int fb = 0; fb < 4; ++fb) rbo[fb] = (colbase + 16 * fb + lr) * 256;
#pragma unroll
    for (int ks = 0; ks < 4; ++ks) koff[ks] = (((ks << 2) + lg) ^ lr) << 4;

    // ---- stage B tile 0 (async) ----
    {
        const f16* g0 = nfh + (size_t)col0e * NFD;
#pragma unroll
        for (int i = 0; i < 8; ++i) gl16(g0 + goffs[i], smem + dbase[i]);
    }

    // ---- A fragments -> registers (tile-invariant): 16 x 4 VGPR ----
    f16x8 ah[4][4];
#pragma unroll
    for (int ks = 0; ks < 4; ++ks)
#pragma unroll
        for (int fa = 0; fa < 4; ++fa) {
            const size_t off = (size_t)(row0 + rowbase + 16 * fa + lr) * NFD + 32 * ks + 8 * lg;
            ah[ks][fa] = *reinterpret_cast<const f16x8*>(nfh + off);
        }

    __syncthreads();   // tile0 + A loads complete

    float stat[4][4];
#pragma unroll
    for (int fa = 0; fa < 4; ++fa)
#pragma unroll
        for (int r = 0; r < 4; ++r) stat[fa][r] = same ? -3.0e38f : 0.0f;
    const float K2 = 1.44269504089f / 0.07f;   // log2(e)/tau
    const float invtau = 1.0f / 0.07f;

#define LOADB(ks_, B_)                                                        \
    {                                                                         \
        _Pragma("unroll")                                                     \
        for (int fb = 0; fb < 4; ++fb)                                        \
            B_[fb] = *(const f16x8*)(bufB + rbo[fb] + koff[ks_]);             \
    }
#define MFMAS(ks_, B_)                                                        \
    {                                                                         \
        __builtin_amdgcn_s_setprio(1);                                        \
        _Pragma("unroll")                                                     \
        for (int fb = 0; fb < 4; ++fb)                                        \
            _Pragma("unroll")                                                 \
            for (int fa = 0; fa < 4; ++fa)                                    \
                acc[fa][fb] = __builtin_amdgcn_mfma_f32_16x16x32_f16(ah[ks_][fa], B_[fb], acc[fa][fb], 0, 0, 0); \
        __builtin_amdgcn_s_setprio(0);                                        \
    }

#pragma unroll 1
    for (int tile = 0; tile < NTILES; ++tile) {
        const char* bufB = smem + (tile & 1) * 32768;

        // issue next-tile stage early (lands during compute, drained at barrier)
        if (tile + 1 < NTILES) {
            char* nb = smem + ((tile + 1) & 1) * 32768;
            const f16* gn = nfh + (size_t)(col0e + (tile + 1) * BCOLS) * NFD;
#pragma unroll
            for (int i = 0; i < 8; ++i) gl16(gn + goffs[i], nb + dbase[i]);
        }

        f32x4 acc[4][4];
#pragma unroll
        for (int fa = 0; fa < 4; ++fa)
#pragma unroll
            for (int fb = 0; fb < 4; ++fb) {
                f32x4 z = {0.0f, 0.0f, 0.0f, 0.0f};
                acc[fa][fb] = z;
            }

        // ks software pipeline: depth-2 prologue, ping-pong B sets
        f16x8 b0[4], b1[4];
        LOADB(0, b0);
        LOADB(1, b1);
        MFMAS(0, b0);
        LOADB(2, b0);
        MFMAS(1, b1);
        LOADB(3, b1);
        MFMAS(2, b0);
        MFMAS(3, b1);

        // fold acc into stat; C/D: col=lane&15, row=4*lg+reg (m89-verified)
        if (same) {
            const int col0 = col0e + tile * BCOLS;
#pragma unroll
            for (int fa = 0; fa < 4; ++fa)
#pragma unroll
                for (int fb = 0; fb < 4; ++fb)
#pragma unroll
                    for (int r = 0; r < 4; ++r) {
                        const int grow = row0 + rowbase + 16 * fa + 4 * lg + r;
                        const int gcol = col0 + colbase + 16 * fb + lr;
                        stat[fa][r] = (grow == gcol) ? stat[fa][r]
                                                     : fmaxf(stat[fa][r], acc[fa][fb][r]);
                    }
        } else {
#pragma unroll
            for (int fa = 0; fa < 4; ++fa)
#pragma unroll
                for (int fb = 0; fb < 4; ++fb)
#pragma unroll
                    for (int r = 0; r < 4; ++r)
                        stat[fa][r] += exp2f(acc[fa][fb][r] * K2);
        }

        __syncthreads();
    }
#undef LOADB
#undef MFMAS

    // reduce over the 16 cols held across lr (lane bits 0..3)
#pragma unroll
    for (int m = 1; m <= 8; m <<= 1) {
#pragma unroll
        for (int fa = 0; fa < 4; ++fa)
#pragma unroll
            for (int r = 0; r < 4; ++r) {
                const float o = __shfl_xor(stat[fa][r], m, 64);
                stat[fa][r] = same ? fmaxf(stat[fa][r], o) : (stat[fa][r] + o);
            }
    }

    // combine the two col-half waves per row via LDS scratch (smem reusable
    // after the final loop barrier)
    float* scratch = (float*)smem;
    if (lr == 0) {
#pragma unroll
        for (int fa = 0; fa < 4; ++fa)
#pragma unroll
            for (int r = 0; r < 4; ++r) {
                const int rl = rowbase + 16 * fa + 4 * lg + r;
                scratch[(w & 1) * 128 + rl] = stat[fa][r];
            }
    }
    __syncthreads();
    if (t < 128) {
        const float v0 = scratch[t];
        const float v1 = scratch[128 + t];
        const float v = same ? fmaxf(v0, v1) * invtau : (v0 + v1);
        (same ? posp : sexpp)[(size_t)p * NBTOT + row0 + t] = v;
    }
}

// ---------------------------------------------------------------------------
// Kernel 3a: per-row loss partials over 32 blocks (avoids 1-CU bottleneck).
// loss_i = log1p(S * exp(-pos))
// ---------------------------------------------------------------------------
__global__ void loss_part(const float* __restrict__ posp, const float* __restrict__ sexpp,
                          float* __restrict__ partial) {
    const int i = blockIdx.x * 256 + threadIdx.x;
    const float pv = fmaxf(fmaxf(posp[i], posp[NBTOT + i]),
                           fmaxf(posp[2 * NBTOT + i], posp[3 * NBTOT + i]));
    const float se = sexpp[i] + sexpp[NBTOT + i] + sexpp[2 * NBTOT + i] + sexpp[3 * NBTOT + i];
    float s = log1pf(se * __expf(-pv));
#pragma unroll
    for (int m = 32; m >= 1; m >>= 1) s += __shfl_xor(s, m, 64);
    __shared__ float part[4];
    if ((threadIdx.x & 63) == 0) part[threadIdx.x >> 6] = s;
    __syncthreads();
    if (threadIdx.x == 0)
        partial[blockIdx.x] = part[0] + part[1] + part[2] + part[3];
}

// Kernel 3b: final combine (1 wave).
__global__ void loss_final(const float* __restrict__ partial, float* __restrict__ out) {
    const int t = threadIdx.x;
    float s = (t < 32) ? partial[t] : 0.0f;
#pragma unroll
    for (int m = 32; m >= 1; m >>= 1) s += __shfl_xor(s, m, 64);
    if (t == 0) out[0] = s / (float)NBTOT;
}

// ---------------------------------------------------------------------------
extern "C" void kernel_launch(void* const* d_in, const int* in_sizes, int n_in,
                              void* d_out, int out_size, void* d_ws, size_t ws_size,
                              hipStream_t stream) {
    const float* f1 = (const float*)d_in[0];
    const float* f2 = (const float*)d_in[1];

    f16*   nfh     = (f16*)d_ws;                         // 8192*128 fp16 = 2 MB
    float* posp    = (float*)(nfh + (size_t)NBTOT * NFD);  // 4*8192 f32
    float* sexpp   = posp + 4 * NBTOT;                     // 4*8192 f32
    float* partial = sexpp + 4 * NBTOT;                    // 32 f32

    (void)hipFuncSetAttribute(reinterpret_cast<const void*>(simstat_mfma),
                              hipFuncAttributeMaxDynamicSharedMemorySize, 65536);

    norm_k<<<NBTOT / 4, 256, 0, stream>>>(f1, f2, nfh);
    simstat_mfma<<<dim3(8, 64), 256, 65536, stream>>>(nfh, posp, sexpp);
    loss_part<<<NBTOT / 256, 256, 0, stream>>>(posp, sexpp, partial);
    loss_final<<<1, 64, 0, stream>>>(partial, (float*)d_out);
}